// Round 1
// baseline (5677.735 us; speedup 1.0000x reference)
//
#include <hip/hip_runtime.h>
#include <hip/hip_bf16.h>

#define NN 10000
#define EE 50000
#define TT 80000
#define DD 16
#define HH 128
#define CC 64

typedef __hip_bfloat16 bf16;

__device__ __forceinline__ float silu_f(float x) { return x / (1.f + __expf(-x)); }
__device__ __forceinline__ float sigm_f(float x) { return 1.f / (1.f + __expf(-x)); }

__device__ __forceinline__ float wave_sum64(float v) {
#pragma unroll
  for (int m = 1; m < 64; m <<= 1) v += __shfl_xor(v, m, 64);
  return v;
}

// K1: h = x @ W_nb + b_nb ; xq = h[:, :64], sigxk = sigmoid(h[:, 64:])
__global__ __launch_bounds__(128) void k_node(
    const float* __restrict__ x, const float* __restrict__ W_nb,
    const float* __restrict__ b_nb, float* __restrict__ xq,
    float* __restrict__ sigxk) {
  __shared__ float xrow[HH];
  const int n = blockIdx.x;
  const int t = threadIdx.x;
  xrow[t] = x[(size_t)n * HH + t];
  __syncthreads();
  float acc = b_nb[t];
#pragma unroll 8
  for (int k = 0; k < HH; ++k) acc = fmaf(xrow[k], W_nb[k * HH + t], acc);
  if (t < CC)
    xq[(size_t)n * CC + t] = acc;
  else
    sigxk[(size_t)n * CC + (t - CC)] = sigm_f(acc);
}

// K2: per (e,d) row: c = silu(silu(row) @ W_c1) @ W_c2
//     cji2 = c[:64] (bf16), ckjn = l2norm(c[64:]) (bf16)
__global__ __launch_bounds__(256) void k_coeffs(
    const float* __restrict__ cji, const float* __restrict__ W_c1,
    const float* __restrict__ W_c2, bf16* __restrict__ cji2,
    bf16* __restrict__ ckjn) {
  const int r = blockIdx.x * 256 + threadIdx.x;
  const int R = EE * DD;
  if (r >= R) return;
  const float* row = cji + (size_t)r * 64;
  float s[64];
#pragma unroll
  for (int k = 0; k < 64; k += 4) {
    const float4 v = *reinterpret_cast<const float4*>(row + k);
    s[k + 0] = silu_f(v.x);
    s[k + 1] = silu_f(v.y);
    s[k + 2] = silu_f(v.z);
    s[k + 3] = silu_f(v.w);
  }
  float t1[64];
#pragma unroll
  for (int jc = 0; jc < 64; jc += 8) {
    float acc[8] = {0.f, 0.f, 0.f, 0.f, 0.f, 0.f, 0.f, 0.f};
#pragma unroll
    for (int k = 0; k < 64; ++k) {
#pragma unroll
      for (int j = 0; j < 8; ++j)
        acc[j] = fmaf(s[k], W_c1[k * 64 + jc + j], acc[j]);
    }
#pragma unroll
    for (int j = 0; j < 8; ++j) t1[jc + j] = silu_f(acc[j]);
  }
  // first half -> cji2
#pragma unroll
  for (int jc = 0; jc < 64; jc += 8) {
    float acc[8] = {0.f, 0.f, 0.f, 0.f, 0.f, 0.f, 0.f, 0.f};
#pragma unroll
    for (int k = 0; k < 64; ++k) {
#pragma unroll
      for (int j = 0; j < 8; ++j)
        acc[j] = fmaf(t1[k], W_c2[k * 128 + jc + j], acc[j]);
    }
    union { bf16 h[8]; uint4 u; } pk;
#pragma unroll
    for (int j = 0; j < 8; ++j) pk.h[j] = __float2bfloat16(acc[j]);
    *reinterpret_cast<uint4*>(cji2 + (size_t)r * 64 + jc) = pk.u;
  }
  // second half -> normalized ckj
  float c2[64];
#pragma unroll
  for (int jc = 0; jc < 64; jc += 8) {
    float acc[8] = {0.f, 0.f, 0.f, 0.f, 0.f, 0.f, 0.f, 0.f};
#pragma unroll
    for (int k = 0; k < 64; ++k) {
#pragma unroll
      for (int j = 0; j < 8; ++j)
        acc[j] = fmaf(t1[k], W_c2[k * 128 + 64 + jc + j], acc[j]);
    }
#pragma unroll
    for (int j = 0; j < 8; ++j) c2[jc + j] = acc[j];
  }
  float ss = 0.f;
#pragma unroll
  for (int j = 0; j < 64; ++j) ss = fmaf(c2[j], c2[j], ss);
  const float rn = 1.f / fmaxf(sqrtf(ss), 1e-12f);
#pragma unroll
  for (int jc = 0; jc < 64; jc += 8) {
    union { bf16 h[8]; uint4 u; } pk;
#pragma unroll
    for (int j = 0; j < 8; ++j) pk.h[j] = __float2bfloat16(c2[jc + j] * rn);
    *reinterpret_cast<uint4*>(ckjn + (size_t)r * 64 + jc) = pk.u;
  }
}

// K3: one wave per triplet. lane = channel h.
__global__ __launch_bounds__(256) void k_triplet(
    const bf16* __restrict__ ckjn, const float* __restrict__ shbs,
    const float* __restrict__ robs, const float* __restrict__ sigxk,
    const int* __restrict__ tri_idx_k, const int* __restrict__ edge_idx_kj,
    const int* __restrict__ edge_idx_ji, float* __restrict__ agg) {
  const int wid = (blockIdx.x * 256 + threadIdx.x) >> 6;
  const int l = threadIdx.x & 63;
  if (wid >= TT) return;
  const int kj = edge_idx_kj[wid];
  const int kn = tri_idx_k[wid];
  const int ji = edge_idx_ji[wid];
  float acc = 0.f;
#pragma unroll
  for (int d = 0; d < DD; ++d) {
    const float w = shbs[(size_t)wid * DD + d] * robs[(size_t)kj * DD + d];
    acc = fmaf(w, __bfloat162float(ckjn[((size_t)kj * DD + d) * CC + l]), acc);
  }
  const float ss = wave_sum64(acc * acc);
  const float rn = 1.f / fmaxf(sqrtf(ss), 1e-12f);
  const float tbw = acc * rn * sigxk[(size_t)kn * CC + l];
  atomicAdd(&agg[(size_t)ji * CC + l], tbw);
}

// K4: one wave per edge: three_lin GEMV, cji3/lcao norms, node-message MLP,
//     atomic scatter lcao*m into node accumulator.
#define K4_BLOCKS 2048
__global__ __launch_bounds__(256) void k_edge(
    const float* __restrict__ agg, const bf16* __restrict__ cji2,
    const float* __restrict__ robs, const float* __restrict__ xq,
    const int* __restrict__ idx_i, const int* __restrict__ idx_j,
    const float* __restrict__ W_t3, const float* __restrict__ b_t3,
    const float* __restrict__ W_n1, const float* __restrict__ b_n1,
    const float* __restrict__ W_n2, const float* __restrict__ b_n2,
    float* __restrict__ lacc) {
  __shared__ float wt3[64 * 64];
  __shared__ float wn1[128 * 64];
  __shared__ float wn2[64 * 64];
  __shared__ float wbuf[4][128];
  for (int i = threadIdx.x; i < 64 * 64; i += 256) wt3[i] = W_t3[i];
  for (int i = threadIdx.x; i < 128 * 64; i += 256) wn1[i] = W_n1[i];
  for (int i = threadIdx.x; i < 64 * 64; i += 256) wn2[i] = W_n2[i];
  __syncthreads();
  const int wid = threadIdx.x >> 6;
  const int l = threadIdx.x & 63;
  const int gw = blockIdx.x * 4 + wid;
  const int stride = K4_BLOCKS * 4;
  const float bt3 = b_t3[l], bn1 = b_n1[l], bn2 = b_n2[l];
  for (int e = gw; e < EE; e += stride) {
    // tbw2 = silu(agg[e]) @ W_t3 + b_t3
    const float a = silu_f(agg[(size_t)e * CC + l]);
    wbuf[wid][l] = a;
    float acc = bt3;
#pragma unroll 8
    for (int k = 0; k < 64; ++k) acc = fmaf(wbuf[wid][k], wt3[k * 64 + l], acc);
    const float onew = 1.f + acc;
    // cji3 = l2norm(cji2 * onew), lcao = l2norm(sum_d robs*cji3)
    float lc = 0.f;
#pragma unroll
    for (int d = 0; d < DD; ++d) {
      const float v =
          __bfloat162float(cji2[((size_t)e * DD + d) * CC + l]) * onew;
      const float ssd = wave_sum64(v * v);
      const float rnd = 1.f / fmaxf(sqrtf(ssd), 1e-12f);
      lc = fmaf(robs[(size_t)e * DD + d] * rnd, v, lc);
    }
    const float ss = wave_sum64(lc * lc);
    const float rn = 1.f / fmaxf(sqrtf(ss), 1e-12f);
    const float lcao = lc * rn;
    // node message m
    const int vi = idx_i[e], vj = idx_j[e];
    const float mi = silu_f(xq[(size_t)vi * CC + l]);
    const float mj = silu_f(xq[(size_t)vj * CC + l]);
    wbuf[wid][l] = mi;
    wbuf[wid][64 + l] = mj;
    float acc2 = bn1;
#pragma unroll 8
    for (int k = 0; k < 128; ++k)
      acc2 = fmaf(wbuf[wid][k], wn1[k * 64 + l], acc2);
    acc2 = silu_f(acc2);
    wbuf[wid][l] = acc2;
    float acc3 = bn2;
#pragma unroll 8
    for (int k = 0; k < 64; ++k)
      acc3 = fmaf(wbuf[wid][k], wn2[k * 64 + l], acc3);
    atomicAdd(&lacc[(size_t)vi * CC + l], lcao * acc3);
  }
}

// K5: out = x + lacc @ W_na
__global__ __launch_bounds__(128) void k_out(
    const float* __restrict__ x, const float* __restrict__ lacc,
    const float* __restrict__ W_na, float* __restrict__ out) {
  __shared__ float lrow[CC];
  const int n = blockIdx.x;
  const int t = threadIdx.x;
  if (t < CC) lrow[t] = lacc[(size_t)n * CC + t];
  __syncthreads();
  float acc = x[(size_t)n * HH + t];
#pragma unroll 8
  for (int k = 0; k < CC; ++k) acc = fmaf(lrow[k], W_na[k * HH + t], acc);
  out[(size_t)n * HH + t] = acc;
}

extern "C" void kernel_launch(void* const* d_in, const int* in_sizes, int n_in,
                              void* d_out, int out_size, void* d_ws,
                              size_t ws_size, hipStream_t stream) {
  const float* x = (const float*)d_in[0];
  const float* cji = (const float*)d_in[1];
  const float* robs = (const float*)d_in[2];
  const float* shbs = (const float*)d_in[3];
  const int* idx_i = (const int*)d_in[4];
  const int* idx_j = (const int*)d_in[5];
  const int* tri_idx_k = (const int*)d_in[6];
  const int* edge_idx_kj = (const int*)d_in[7];
  const int* edge_idx_ji = (const int*)d_in[8];
  const float* W_nb = (const float*)d_in[9];
  const float* b_nb = (const float*)d_in[10];
  const float* W_c1 = (const float*)d_in[11];
  const float* W_c2 = (const float*)d_in[12];
  const float* W_t3 = (const float*)d_in[13];
  const float* b_t3 = (const float*)d_in[14];
  const float* W_n1 = (const float*)d_in[15];
  const float* b_n1 = (const float*)d_in[16];
  const float* W_n2 = (const float*)d_in[17];
  const float* b_n2 = (const float*)d_in[18];
  const float* W_na = (const float*)d_in[19];
  float* out = (float*)d_out;

  char* ws = (char*)d_ws;
  const size_t NC4 = (size_t)NN * CC * 4;          // 2,560,000
  const size_t EDC2 = (size_t)EE * DD * CC * 2;    // 102,400,000
  const size_t EC4 = (size_t)EE * CC * 4;          // 12,800,000
  float* xq = (float*)(ws);
  float* sigxk = (float*)(ws + NC4);
  bf16* cji2 = (bf16*)(ws + 2 * NC4);
  bf16* ckjn = (bf16*)(ws + 2 * NC4 + EDC2);
  float* agg = (float*)(ws + 2 * NC4 + 2 * EDC2);
  float* lacc = (float*)(ws + 2 * NC4 + 2 * EDC2 + EC4);

  // zero the two accumulation buffers (adjacent) every call
  hipMemsetAsync(agg, 0, EC4 + NC4, stream);

  k_node<<<NN, 128, 0, stream>>>(x, W_nb, b_nb, xq, sigxk);
  k_coeffs<<<(EE * DD + 255) / 256, 256, 0, stream>>>(cji, W_c1, W_c2, cji2,
                                                      ckjn);
  k_triplet<<<(TT + 3) / 4, 256, 0, stream>>>(ckjn, shbs, robs, sigxk,
                                              tri_idx_k, edge_idx_kj,
                                              edge_idx_ji, agg);
  k_edge<<<K4_BLOCKS, 256, 0, stream>>>(agg, cji2, robs, xq, idx_i, idx_j,
                                        W_t3, b_t3, W_n1, b_n1, W_n2, b_n2,
                                        lacc);
  k_out<<<NN, 128, 0, stream>>>(x, lacc, W_na, out);
}

// Round 2
// 408.387 us; speedup vs baseline: 13.9028x; 13.9028x over previous
//
#include <hip/hip_runtime.h>
#include <hip/hip_bf16.h>

#define NN 10000
#define EE 50000
#define TT 80000
#define DD 16
#define HH 128
#define CC 64

typedef __hip_bfloat16 bf16;
typedef __attribute__((ext_vector_type(8))) short bf16x8;
typedef __attribute__((ext_vector_type(4))) float f32x4;

__device__ __forceinline__ float silu_f(float x) { return x / (1.f + __expf(-x)); }
__device__ __forceinline__ float sigm_f(float x) { return 1.f / (1.f + __expf(-x)); }

__device__ __forceinline__ short f2bs(float x) {
  __hip_bfloat16 h = __float2bfloat16(x);
  short s;
  __builtin_memcpy(&s, &h, 2);
  return s;
}

__device__ __forceinline__ float wave_sum64(float v) {
#pragma unroll
  for (int m = 1; m < 64; m <<= 1) v += __shfl_xor(v, m, 64);
  return v;
}

// K1: h = x @ W_nb + b_nb ; xq = h[:, :64], sigxk = sigmoid(h[:, 64:])
__global__ __launch_bounds__(128) void k_node(
    const float* __restrict__ x, const float* __restrict__ W_nb,
    const float* __restrict__ b_nb, float* __restrict__ xq,
    float* __restrict__ sigxk) {
  __shared__ float xrow[HH];
  const int n = blockIdx.x;
  const int t = threadIdx.x;
  xrow[t] = x[(size_t)n * HH + t];
  __syncthreads();
  float acc = b_nb[t];
#pragma unroll 8
  for (int k = 0; k < HH; ++k) acc = fmaf(xrow[k], W_nb[k * HH + t], acc);
  if (t < CC)
    xq[(size_t)n * CC + t] = acc;
  else
    sigxk[(size_t)n * CC + (t - CC)] = sigm_f(acc);
}

// K2 (MFMA): per 16-row tile of the [E*D, 64] matrix:
//   t1 = silu(silu(A) @ W_c1)   [16,64]
//   c  = t1 @ W_c2              [16,128]
//   cji2 = bf16(c[:, :64]); ckjn = bf16(l2norm_row(c[:, 64:]))
// Weights live in VGPR B-fragments; per-wave LDS buffer handles the
// D->A fragment transpose and coalesced output staging.
#define K2_BLOCKS 2048
#define K2_TILES 50000  // (EE*DD)/16
__global__ __launch_bounds__(256, 2) void k_coeffs(
    const float* __restrict__ cji, const float* __restrict__ W_c1,
    const float* __restrict__ W_c2, bf16* __restrict__ cji2,
    bf16* __restrict__ ckjn) {
  __shared__ __align__(16) short xbuf[4][16 * 72];  // 72-short row stride: 16B aligned, bank-spread
  const int tid = threadIdx.x;
  const int w = tid >> 6, l = tid & 63;
  const int lr = l & 15, lg = l >> 4;  // fragment row/col index, k-group
  short* mybuf = xbuf[w];

  // --- one-time: weight B-fragments into VGPRs ---
  // B layout for mfma_f32_16x16x32_bf16: col = lane&15, k = (lane>>4)*8 + b
  bf16x8 b1[2][4];   // W_c1 [64][64]
  bf16x8 b2[2][8];   // W_c2 [64][128]
#pragma unroll
  for (int kt = 0; kt < 2; ++kt) {
#pragma unroll
    for (int nt = 0; nt < 4; ++nt) {
      bf16x8 t;
#pragma unroll
      for (int b = 0; b < 8; ++b)
        t[b] = f2bs(W_c1[(kt * 32 + lg * 8 + b) * 64 + nt * 16 + lr]);
      b1[kt][nt] = t;
    }
#pragma unroll
    for (int nt = 0; nt < 8; ++nt) {
      bf16x8 t;
#pragma unroll
      for (int b = 0; b < 8; ++b)
        t[b] = f2bs(W_c2[(kt * 32 + lg * 8 + b) * 128 + nt * 16 + lr]);
      b2[kt][nt] = t;
    }
  }

  const int nwave = K2_BLOCKS * 4;
  int tile = blockIdx.x * 4 + w;
  if (tile >= K2_TILES) return;

  // prefetch first tile's A rows (raw fp32)
  float4 r0, r1, r2, r3;
  {
    const float* Ab = cji + (size_t)tile * 16 * 64 + lr * 64 + lg * 8;
    r0 = *(const float4*)(Ab);
    r1 = *(const float4*)(Ab + 4);
    r2 = *(const float4*)(Ab + 32);
    r3 = *(const float4*)(Ab + 36);
  }

  for (; tile < K2_TILES; tile += nwave) {
    // consume raw -> silu -> bf16 A-fragments (row = lane&15, k = lg*8+b)
    bf16x8 a0, a1;
    a0[0] = f2bs(silu_f(r0.x)); a0[1] = f2bs(silu_f(r0.y));
    a0[2] = f2bs(silu_f(r0.z)); a0[3] = f2bs(silu_f(r0.w));
    a0[4] = f2bs(silu_f(r1.x)); a0[5] = f2bs(silu_f(r1.y));
    a0[6] = f2bs(silu_f(r1.z)); a0[7] = f2bs(silu_f(r1.w));
    a1[0] = f2bs(silu_f(r2.x)); a1[1] = f2bs(silu_f(r2.y));
    a1[2] = f2bs(silu_f(r2.z)); a1[3] = f2bs(silu_f(r2.w));
    a1[4] = f2bs(silu_f(r3.x)); a1[5] = f2bs(silu_f(r3.y));
    a1[6] = f2bs(silu_f(r3.z)); a1[7] = f2bs(silu_f(r3.w));

    // issue next tile's loads early (overlap with MFMA work)
    const int next = tile + nwave;
    if (next < K2_TILES) {
      const float* Ab = cji + (size_t)next * 16 * 64 + lr * 64 + lg * 8;
      r0 = *(const float4*)(Ab);
      r1 = *(const float4*)(Ab + 4);
      r2 = *(const float4*)(Ab + 32);
      r3 = *(const float4*)(Ab + 36);
    }

    // GEMM1: [16,64] @ [64,64]
    f32x4 acc1[4];
#pragma unroll
    for (int nt = 0; nt < 4; ++nt) acc1[nt] = (f32x4){0.f, 0.f, 0.f, 0.f};
#pragma unroll
    for (int nt = 0; nt < 4; ++nt) {
      acc1[nt] = __builtin_amdgcn_mfma_f32_16x16x32_bf16(a0, b1[0][nt], acc1[nt], 0, 0, 0);
      acc1[nt] = __builtin_amdgcn_mfma_f32_16x16x32_bf16(a1, b1[1][nt], acc1[nt], 0, 0, 0);
    }

    // silu + transpose D-layout -> A-layout via per-wave LDS
#pragma unroll
    for (int nt = 0; nt < 4; ++nt)
#pragma unroll
      for (int j = 0; j < 4; ++j)
        mybuf[(lg * 4 + j) * 72 + nt * 16 + lr] = f2bs(silu_f(acc1[nt][j]));

    bf16x8 a20 = *(const bf16x8*)(mybuf + lr * 72 + lg * 8);
    bf16x8 a21 = *(const bf16x8*)(mybuf + lr * 72 + 32 + lg * 8);

    // GEMM2: [16,64] @ [64,128]
    f32x4 acc2[8];
#pragma unroll
    for (int nt = 0; nt < 8; ++nt) acc2[nt] = (f32x4){0.f, 0.f, 0.f, 0.f};
#pragma unroll
    for (int nt = 0; nt < 8; ++nt) {
      acc2[nt] = __builtin_amdgcn_mfma_f32_16x16x32_bf16(a20, b2[0][nt], acc2[nt], 0, 0, 0);
      acc2[nt] = __builtin_amdgcn_mfma_f32_16x16x32_bf16(a21, b2[1][nt], acc2[nt], 0, 0, 0);
    }

    // row L2-norm of second half (cols 64..127): per reg-row j, sum over 64 cols
    float rn[4];
#pragma unroll
    for (int j = 0; j < 4; ++j) {
      float ss = acc2[4][j] * acc2[4][j];
      ss = fmaf(acc2[5][j], acc2[5][j], ss);
      ss = fmaf(acc2[6][j], acc2[6][j], ss);
      ss = fmaf(acc2[7][j], acc2[7][j], ss);
#pragma unroll
      for (int m = 1; m < 16; m <<= 1) ss += __shfl_xor(ss, m, 64);
      rn[j] = 1.f / fmaxf(sqrtf(ss), 1e-12f);
    }

    // stage each 64-col half in LDS, then coalesced 32B-per-lane store
#pragma unroll
    for (int half = 0; half < 2; ++half) {
#pragma unroll
      for (int nt = 0; nt < 4; ++nt)
#pragma unroll
        for (int j = 0; j < 4; ++j) {
          const float v = half ? acc2[4 + nt][j] * rn[j] : acc2[nt][j];
          mybuf[(lg * 4 + j) * 72 + nt * 16 + lr] = f2bs(v);
        }
      bf16* dst = (half ? ckjn : cji2) + (size_t)tile * 16 * 64;
      const int row = l >> 2, cs = (l & 3) * 16;
      const uint4 u0 = *(const uint4*)(mybuf + row * 72 + cs);
      const uint4 u1 = *(const uint4*)(mybuf + row * 72 + cs + 8);
      *(uint4*)(dst + row * 64 + cs) = u0;
      *(uint4*)(dst + row * 64 + cs + 8) = u1;
    }
  }
}

// K3: one wave per triplet. lane = channel h.
__global__ __launch_bounds__(256) void k_triplet(
    const bf16* __restrict__ ckjn, const float* __restrict__ shbs,
    const float* __restrict__ robs, const float* __restrict__ sigxk,
    const int* __restrict__ tri_idx_k, const int* __restrict__ edge_idx_kj,
    const int* __restrict__ edge_idx_ji, float* __restrict__ agg) {
  const int wid = (blockIdx.x * 256 + threadIdx.x) >> 6;
  const int l = threadIdx.x & 63;
  if (wid >= TT) return;
  const int kj = edge_idx_kj[wid];
  const int kn = tri_idx_k[wid];
  const int ji = edge_idx_ji[wid];
  float acc = 0.f;
#pragma unroll
  for (int d = 0; d < DD; ++d) {
    const float w = shbs[(size_t)wid * DD + d] * robs[(size_t)kj * DD + d];
    acc = fmaf(w, __bfloat162float(ckjn[((size_t)kj * DD + d) * CC + l]), acc);
  }
  const float ss = wave_sum64(acc * acc);
  const float rn = 1.f / fmaxf(sqrtf(ss), 1e-12f);
  const float tbw = acc * rn * sigxk[(size_t)kn * CC + l];
  atomicAdd(&agg[(size_t)ji * CC + l], tbw);
}

// K4: one wave per edge: three_lin GEMV, cji3/lcao norms, node-message MLP,
//     atomic scatter lcao*m into node accumulator.
#define K4_BLOCKS 2048
__global__ __launch_bounds__(256) void k_edge(
    const float* __restrict__ agg, const bf16* __restrict__ cji2,
    const float* __restrict__ robs, const float* __restrict__ xq,
    const int* __restrict__ idx_i, const int* __restrict__ idx_j,
    const float* __restrict__ W_t3, const float* __restrict__ b_t3,
    const float* __restrict__ W_n1, const float* __restrict__ b_n1,
    const float* __restrict__ W_n2, const float* __restrict__ b_n2,
    float* __restrict__ lacc) {
  __shared__ float wt3[64 * 64];
  __shared__ float wn1[128 * 64];
  __shared__ float wn2[64 * 64];
  __shared__ float wbuf[4][128];
  for (int i = threadIdx.x; i < 64 * 64; i += 256) wt3[i] = W_t3[i];
  for (int i = threadIdx.x; i < 128 * 64; i += 256) wn1[i] = W_n1[i];
  for (int i = threadIdx.x; i < 64 * 64; i += 256) wn2[i] = W_n2[i];
  __syncthreads();
  const int wid = threadIdx.x >> 6;
  const int l = threadIdx.x & 63;
  const int gw = blockIdx.x * 4 + wid;
  const int stride = K4_BLOCKS * 4;
  const float bt3 = b_t3[l], bn1 = b_n1[l], bn2 = b_n2[l];
  for (int e = gw; e < EE; e += stride) {
    // tbw2 = silu(agg[e]) @ W_t3 + b_t3
    const float a = silu_f(agg[(size_t)e * CC + l]);
    wbuf[wid][l] = a;
    float acc = bt3;
#pragma unroll 8
    for (int k = 0; k < 64; ++k) acc = fmaf(wbuf[wid][k], wt3[k * 64 + l], acc);
    const float onew = 1.f + acc;
    // cji3 = l2norm(cji2 * onew), lcao = l2norm(sum_d robs*cji3)
    float lc = 0.f;
#pragma unroll
    for (int d = 0; d < DD; ++d) {
      const float v =
          __bfloat162float(cji2[((size_t)e * DD + d) * CC + l]) * onew;
      const float ssd = wave_sum64(v * v);
      const float rnd = 1.f / fmaxf(sqrtf(ssd), 1e-12f);
      lc = fmaf(robs[(size_t)e * DD + d] * rnd, v, lc);
    }
    const float ss = wave_sum64(lc * lc);
    const float rn = 1.f / fmaxf(sqrtf(ss), 1e-12f);
    const float lcao = lc * rn;
    // node message m
    const int vi = idx_i[e], vj = idx_j[e];
    const float mi = silu_f(xq[(size_t)vi * CC + l]);
    const float mj = silu_f(xq[(size_t)vj * CC + l]);
    wbuf[wid][l] = mi;
    wbuf[wid][64 + l] = mj;
    float acc2 = bn1;
#pragma unroll 8
    for (int k = 0; k < 128; ++k)
      acc2 = fmaf(wbuf[wid][k], wn1[k * 64 + l], acc2);
    acc2 = silu_f(acc2);
    wbuf[wid][l] = acc2;
    float acc3 = bn2;
#pragma unroll 8
    for (int k = 0; k < 64; ++k)
      acc3 = fmaf(wbuf[wid][k], wn2[k * 64 + l], acc3);
    atomicAdd(&lacc[(size_t)vi * CC + l], lcao * acc3);
  }
}

// K5: out = x + lacc @ W_na
__global__ __launch_bounds__(128) void k_out(
    const float* __restrict__ x, const float* __restrict__ lacc,
    const float* __restrict__ W_na, float* __restrict__ out) {
  __shared__ float lrow[CC];
  const int n = blockIdx.x;
  const int t = threadIdx.x;
  if (t < CC) lrow[t] = lacc[(size_t)n * CC + t];
  __syncthreads();
  float acc = x[(size_t)n * HH + t];
#pragma unroll 8
  for (int k = 0; k < CC; ++k) acc = fmaf(lrow[k], W_na[k * HH + t], acc);
  out[(size_t)n * HH + t] = acc;
}

extern "C" void kernel_launch(void* const* d_in, const int* in_sizes, int n_in,
                              void* d_out, int out_size, void* d_ws,
                              size_t ws_size, hipStream_t stream) {
  const float* x = (const float*)d_in[0];
  const float* cji = (const float*)d_in[1];
  const float* robs = (const float*)d_in[2];
  const float* shbs = (const float*)d_in[3];
  const int* idx_i = (const int*)d_in[4];
  const int* idx_j = (const int*)d_in[5];
  const int* tri_idx_k = (const int*)d_in[6];
  const int* edge_idx_kj = (const int*)d_in[7];
  const int* edge_idx_ji = (const int*)d_in[8];
  const float* W_nb = (const float*)d_in[9];
  const float* b_nb = (const float*)d_in[10];
  const float* W_c1 = (const float*)d_in[11];
  const float* W_c2 = (const float*)d_in[12];
  const float* W_t3 = (const float*)d_in[13];
  const float* b_t3 = (const float*)d_in[14];
  const float* W_n1 = (const float*)d_in[15];
  const float* b_n1 = (const float*)d_in[16];
  const float* W_n2 = (const float*)d_in[17];
  const float* b_n2 = (const float*)d_in[18];
  const float* W_na = (const float*)d_in[19];
  float* out = (float*)d_out;

  char* ws = (char*)d_ws;
  const size_t NC4 = (size_t)NN * CC * 4;          // 2,560,000
  const size_t EDC2 = (size_t)EE * DD * CC * 2;    // 102,400,000
  const size_t EC4 = (size_t)EE * CC * 4;          // 12,800,000
  float* xq = (float*)(ws);
  float* sigxk = (float*)(ws + NC4);
  bf16* cji2 = (bf16*)(ws + 2 * NC4);
  bf16* ckjn = (bf16*)(ws + 2 * NC4 + EDC2);
  float* agg = (float*)(ws + 2 * NC4 + 2 * EDC2);
  float* lacc = (float*)(ws + 2 * NC4 + 2 * EDC2 + EC4);

  // zero the two accumulation buffers (adjacent) every call
  hipMemsetAsync(agg, 0, EC4 + NC4, stream);

  k_node<<<NN, 128, 0, stream>>>(x, W_nb, b_nb, xq, sigxk);
  k_coeffs<<<K2_BLOCKS, 256, 0, stream>>>(cji, W_c1, W_c2, cji2, ckjn);
  k_triplet<<<(TT + 3) / 4, 256, 0, stream>>>(ckjn, shbs, robs, sigxk,
                                              tri_idx_k, edge_idx_kj,
                                              edge_idx_ji, agg);
  k_edge<<<K4_BLOCKS, 256, 0, stream>>>(agg, cji2, robs, xq, idx_i, idx_j,
                                        W_t3, b_t3, W_n1, b_n1, W_n2, b_n2,
                                        lacc);
  k_out<<<NN, 128, 0, stream>>>(x, lacc, W_na, out);
}

// Round 3
// 280.715 us; speedup vs baseline: 20.2260x; 1.4548x over previous
//
#include <hip/hip_runtime.h>
#include <hip/hip_bf16.h>

#define NN 10000
#define EE 50000
#define TT 80000
#define DD 16
#define HH 128
#define CC 64

typedef __hip_bfloat16 bf16;
typedef __attribute__((ext_vector_type(8))) short bf16x8;
typedef __attribute__((ext_vector_type(4))) float f32x4;

__device__ __forceinline__ float silu_f(float x) { return x / (1.f + __expf(-x)); }
__device__ __forceinline__ float sigm_f(float x) { return 1.f / (1.f + __expf(-x)); }

__device__ __forceinline__ short f2bs(float x) {
  __hip_bfloat16 h = __float2bfloat16(x);
  short s;
  __builtin_memcpy(&s, &h, 2);
  return s;
}

__device__ __forceinline__ float rnorm_f(float ss) {
  // 1 / max(sqrt(ss), 1e-12) via fast transcendentals
  return __builtin_amdgcn_rcpf(fmaxf(__builtin_amdgcn_sqrtf(ss), 1e-12f));
}

__device__ __forceinline__ float wave_sum64(float v) {
#pragma unroll
  for (int m = 1; m < 64; m <<= 1) v += __shfl_xor(v, m, 64);
  return v;
}

// K1: h = x @ W_nb + b_nb ; sxq = silu(h[:, :64]), sigxk = sigmoid(h[:, 64:])
__global__ __launch_bounds__(128) void k_node(
    const float* __restrict__ x, const float* __restrict__ W_nb,
    const float* __restrict__ b_nb, float* __restrict__ sxq,
    float* __restrict__ sigxk) {
  __shared__ float xrow[HH];
  const int n = blockIdx.x;
  const int t = threadIdx.x;
  xrow[t] = x[(size_t)n * HH + t];
  __syncthreads();
  float acc = b_nb[t];
#pragma unroll 8
  for (int k = 0; k < HH; ++k) acc = fmaf(xrow[k], W_nb[k * HH + t], acc);
  if (t < CC)
    sxq[(size_t)n * CC + t] = silu_f(acc);
  else
    sigxk[(size_t)n * CC + (t - CC)] = sigm_f(acc);
}

// K2 (MFMA): coeffs MLP over the [E*D, 64] matrix, 16-row tiles.
#define K2_BLOCKS 2048
#define K2_TILES 50000  // (EE*DD)/16
__global__ __launch_bounds__(256, 2) void k_coeffs(
    const float* __restrict__ cji, const float* __restrict__ W_c1,
    const float* __restrict__ W_c2, bf16* __restrict__ cji2,
    bf16* __restrict__ ckjn) {
  __shared__ __align__(16) short xbuf[4][16 * 72];
  const int tid = threadIdx.x;
  const int w = tid >> 6, l = tid & 63;
  const int lr = l & 15, lg = l >> 4;
  short* mybuf = xbuf[w];

  bf16x8 b1[2][4];   // W_c1 [64][64]
  bf16x8 b2[2][8];   // W_c2 [64][128]
#pragma unroll
  for (int kt = 0; kt < 2; ++kt) {
#pragma unroll
    for (int nt = 0; nt < 4; ++nt) {
      bf16x8 t;
#pragma unroll
      for (int b = 0; b < 8; ++b)
        t[b] = f2bs(W_c1[(kt * 32 + lg * 8 + b) * 64 + nt * 16 + lr]);
      b1[kt][nt] = t;
    }
#pragma unroll
    for (int nt = 0; nt < 8; ++nt) {
      bf16x8 t;
#pragma unroll
      for (int b = 0; b < 8; ++b)
        t[b] = f2bs(W_c2[(kt * 32 + lg * 8 + b) * 128 + nt * 16 + lr]);
      b2[kt][nt] = t;
    }
  }

  const int nwave = K2_BLOCKS * 4;
  int tile = blockIdx.x * 4 + w;
  if (tile >= K2_TILES) return;

  float4 r0, r1, r2, r3;
  {
    const float* Ab = cji + (size_t)tile * 16 * 64 + lr * 64 + lg * 8;
    r0 = *(const float4*)(Ab);
    r1 = *(const float4*)(Ab + 4);
    r2 = *(const float4*)(Ab + 32);
    r3 = *(const float4*)(Ab + 36);
  }

  for (; tile < K2_TILES; tile += nwave) {
    bf16x8 a0, a1;
    a0[0] = f2bs(silu_f(r0.x)); a0[1] = f2bs(silu_f(r0.y));
    a0[2] = f2bs(silu_f(r0.z)); a0[3] = f2bs(silu_f(r0.w));
    a0[4] = f2bs(silu_f(r1.x)); a0[5] = f2bs(silu_f(r1.y));
    a0[6] = f2bs(silu_f(r1.z)); a0[7] = f2bs(silu_f(r1.w));
    a1[0] = f2bs(silu_f(r2.x)); a1[1] = f2bs(silu_f(r2.y));
    a1[2] = f2bs(silu_f(r2.z)); a1[3] = f2bs(silu_f(r2.w));
    a1[4] = f2bs(silu_f(r3.x)); a1[5] = f2bs(silu_f(r3.y));
    a1[6] = f2bs(silu_f(r3.z)); a1[7] = f2bs(silu_f(r3.w));

    const int next = tile + nwave;
    if (next < K2_TILES) {
      const float* Ab = cji + (size_t)next * 16 * 64 + lr * 64 + lg * 8;
      r0 = *(const float4*)(Ab);
      r1 = *(const float4*)(Ab + 4);
      r2 = *(const float4*)(Ab + 32);
      r3 = *(const float4*)(Ab + 36);
    }

    f32x4 acc1[4];
#pragma unroll
    for (int nt = 0; nt < 4; ++nt) acc1[nt] = (f32x4){0.f, 0.f, 0.f, 0.f};
#pragma unroll
    for (int nt = 0; nt < 4; ++nt) {
      acc1[nt] = __builtin_amdgcn_mfma_f32_16x16x32_bf16(a0, b1[0][nt], acc1[nt], 0, 0, 0);
      acc1[nt] = __builtin_amdgcn_mfma_f32_16x16x32_bf16(a1, b1[1][nt], acc1[nt], 0, 0, 0);
    }

#pragma unroll
    for (int nt = 0; nt < 4; ++nt)
#pragma unroll
      for (int j = 0; j < 4; ++j)
        mybuf[(lg * 4 + j) * 72 + nt * 16 + lr] = f2bs(silu_f(acc1[nt][j]));

    bf16x8 a20 = *(const bf16x8*)(mybuf + lr * 72 + lg * 8);
    bf16x8 a21 = *(const bf16x8*)(mybuf + lr * 72 + 32 + lg * 8);

    f32x4 acc2[8];
#pragma unroll
    for (int nt = 0; nt < 8; ++nt) acc2[nt] = (f32x4){0.f, 0.f, 0.f, 0.f};
#pragma unroll
    for (int nt = 0; nt < 8; ++nt) {
      acc2[nt] = __builtin_amdgcn_mfma_f32_16x16x32_bf16(a20, b2[0][nt], acc2[nt], 0, 0, 0);
      acc2[nt] = __builtin_amdgcn_mfma_f32_16x16x32_bf16(a21, b2[1][nt], acc2[nt], 0, 0, 0);
    }

    float rn[4];
#pragma unroll
    for (int j = 0; j < 4; ++j) {
      float ss = acc2[4][j] * acc2[4][j];
      ss = fmaf(acc2[5][j], acc2[5][j], ss);
      ss = fmaf(acc2[6][j], acc2[6][j], ss);
      ss = fmaf(acc2[7][j], acc2[7][j], ss);
#pragma unroll
      for (int m = 1; m < 16; m <<= 1) ss += __shfl_xor(ss, m, 64);
      rn[j] = rnorm_f(ss);
    }

#pragma unroll
    for (int half = 0; half < 2; ++half) {
#pragma unroll
      for (int nt = 0; nt < 4; ++nt)
#pragma unroll
        for (int j = 0; j < 4; ++j) {
          const float v = half ? acc2[4 + nt][j] * rn[j] : acc2[nt][j];
          mybuf[(lg * 4 + j) * 72 + nt * 16 + lr] = f2bs(v);
        }
      bf16* dst = (half ? ckjn : cji2) + (size_t)tile * 16 * 64;
      const int row = l >> 2, cs = (l & 3) * 16;
      const uint4 u0 = *(const uint4*)(mybuf + row * 72 + cs);
      const uint4 u1 = *(const uint4*)(mybuf + row * 72 + cs + 8);
      *(uint4*)(dst + row * 64 + cs) = u0;
      *(uint4*)(dst + row * 64 + cs + 8) = u1;
    }
  }
}

// K3: one wave per triplet. lane = channel h.
__global__ __launch_bounds__(256) void k_triplet(
    const bf16* __restrict__ ckjn, const float* __restrict__ shbs,
    const float* __restrict__ robs, const float* __restrict__ sigxk,
    const int* __restrict__ tri_idx_k, const int* __restrict__ edge_idx_kj,
    const int* __restrict__ edge_idx_ji, float* __restrict__ agg) {
  const int wid = (blockIdx.x * 256 + threadIdx.x) >> 6;
  const int l = threadIdx.x & 63;
  if (wid >= TT) return;
  const int kj = edge_idx_kj[wid];
  const int kn = tri_idx_k[wid];
  const int ji = edge_idx_ji[wid];
  float4 sh[4], rb[4];
#pragma unroll
  for (int q = 0; q < 4; ++q) {
    sh[q] = *(const float4*)(shbs + (size_t)wid * DD + q * 4);
    rb[q] = *(const float4*)(robs + (size_t)kj * DD + q * 4);
  }
  float acc = 0.f;
#pragma unroll
  for (int d = 0; d < DD; ++d) {
    const float shv = (d & 2) ? ((d & 1) ? sh[d >> 2].w : sh[d >> 2].z)
                              : ((d & 1) ? sh[d >> 2].y : sh[d >> 2].x);
    const float rbv = (d & 2) ? ((d & 1) ? rb[d >> 2].w : rb[d >> 2].z)
                              : ((d & 1) ? rb[d >> 2].y : rb[d >> 2].x);
    acc = fmaf(shv * rbv,
               __bfloat162float(ckjn[((size_t)kj * DD + d) * CC + l]), acc);
  }
  const float ss = wave_sum64(acc * acc);
  const float tbw = acc * rnorm_f(ss) * sigxk[(size_t)kn * CC + l];
  atomicAdd(&agg[(size_t)ji * CC + l], tbw);
}

// K4a (MFMA, 16 edges/wave): onew = 1 + silu(agg)@W_t3 + b_t3
//                            m    = silu(silu-cat(sxq_i,sxq_j)@W_n1+b_n1)@W_n2+b_n2
#define K4A_TILES 3125  // EE/16
__global__ __launch_bounds__(256, 2) void k_edge_a(
    const float* __restrict__ agg, const float* __restrict__ sxq,
    const int* __restrict__ idx_i, const int* __restrict__ idx_j,
    const float* __restrict__ W_t3, const float* __restrict__ b_t3,
    const float* __restrict__ W_n1, const float* __restrict__ b_n1,
    const float* __restrict__ W_n2, const float* __restrict__ b_n2,
    float* __restrict__ onew_buf, float* __restrict__ m_buf) {
  __shared__ __align__(16) float fbuf[4][16 * 68];
  __shared__ __align__(16) short sbuf[4][16 * 72];
  const int tid = threadIdx.x;
  const int w = tid >> 6, l = tid & 63;
  const int lr = l & 15, lg = l >> 4;
  float* fb = fbuf[w];
  short* sb = sbuf[w];
  const int tile = blockIdx.x * 4 + w;
  if (tile >= K4A_TILES) return;

  // weight B-fragments
  bf16x8 bt3[2][4], bn1[4][4], bn2[2][4];
#pragma unroll
  for (int kt = 0; kt < 2; ++kt)
#pragma unroll
    for (int nt = 0; nt < 4; ++nt) {
      bf16x8 t;
#pragma unroll
      for (int b = 0; b < 8; ++b)
        t[b] = f2bs(W_t3[(kt * 32 + lg * 8 + b) * 64 + nt * 16 + lr]);
      bt3[kt][nt] = t;
    }
#pragma unroll
  for (int kt = 0; kt < 4; ++kt)
#pragma unroll
    for (int nt = 0; nt < 4; ++nt) {
      bf16x8 t;
#pragma unroll
      for (int b = 0; b < 8; ++b)
        t[b] = f2bs(W_n1[(kt * 32 + lg * 8 + b) * 64 + nt * 16 + lr]);
      bn1[kt][nt] = t;
    }
#pragma unroll
  for (int kt = 0; kt < 2; ++kt)
#pragma unroll
    for (int nt = 0; nt < 4; ++nt) {
      bf16x8 t;
#pragma unroll
      for (int b = 0; b < 8; ++b)
        t[b] = f2bs(W_n2[(kt * 32 + lg * 8 + b) * 64 + nt * 16 + lr]);
      bn2[kt][nt] = t;
    }
  float bt3c[4], bn1c[4], bn2c[4];
#pragma unroll
  for (int nt = 0; nt < 4; ++nt) {
    bt3c[nt] = b_t3[nt * 16 + lr];
    bn1c[nt] = b_n1[nt * 16 + lr];
    bn2c[nt] = b_n2[nt * 16 + lr];
  }

  const int e = tile * 16 + lr;
  const int vi = idx_i[e], vj = idx_j[e];

  // GEMM1: silu(agg) @ W_t3
  bf16x8 aagg[2];
#pragma unroll
  for (int kt = 0; kt < 2; ++kt) {
    const float4 u = *(const float4*)(agg + (size_t)e * 64 + kt * 32 + lg * 8);
    const float4 v = *(const float4*)(agg + (size_t)e * 64 + kt * 32 + lg * 8 + 4);
    bf16x8 t;
    t[0] = f2bs(silu_f(u.x)); t[1] = f2bs(silu_f(u.y));
    t[2] = f2bs(silu_f(u.z)); t[3] = f2bs(silu_f(u.w));
    t[4] = f2bs(silu_f(v.x)); t[5] = f2bs(silu_f(v.y));
    t[6] = f2bs(silu_f(v.z)); t[7] = f2bs(silu_f(v.w));
    aagg[kt] = t;
  }
  f32x4 acc[4];
#pragma unroll
  for (int nt = 0; nt < 4; ++nt) acc[nt] = (f32x4){0.f, 0.f, 0.f, 0.f};
#pragma unroll
  for (int nt = 0; nt < 4; ++nt) {
    acc[nt] = __builtin_amdgcn_mfma_f32_16x16x32_bf16(aagg[0], bt3[0][nt], acc[nt], 0, 0, 0);
    acc[nt] = __builtin_amdgcn_mfma_f32_16x16x32_bf16(aagg[1], bt3[1][nt], acc[nt], 0, 0, 0);
  }
  // onew = 1 + bias + acc, stage f32 -> coalesced store
#pragma unroll
  for (int nt = 0; nt < 4; ++nt)
#pragma unroll
    for (int j = 0; j < 4; ++j)
      fb[(lg * 4 + j) * 68 + nt * 16 + lr] = 1.f + bt3c[nt] + acc[nt][j];
  {
    const int row = l >> 2, cs = (l & 3) * 16;
    float* dst = onew_buf + (size_t)(tile * 16 + row) * 64 + cs;
#pragma unroll
    for (int q = 0; q < 4; ++q)
      *(float4*)(dst + q * 4) = *(const float4*)(fb + row * 68 + cs + q * 4);
  }

  // GEMM2: [sxq_i | sxq_j] @ W_n1
  bf16x8 am[4];
#pragma unroll
  for (int kt = 0; kt < 4; ++kt) {
    const float* src = (kt < 2) ? (sxq + (size_t)vi * 64 + kt * 32)
                                : (sxq + (size_t)vj * 64 + (kt - 2) * 32);
    const float4 u = *(const float4*)(src + lg * 8);
    const float4 v = *(const float4*)(src + lg * 8 + 4);
    bf16x8 t;
    t[0] = f2bs(u.x); t[1] = f2bs(u.y); t[2] = f2bs(u.z); t[3] = f2bs(u.w);
    t[4] = f2bs(v.x); t[5] = f2bs(v.y); t[6] = f2bs(v.z); t[7] = f2bs(v.w);
    am[kt] = t;
  }
  f32x4 acc1[4];
#pragma unroll
  for (int nt = 0; nt < 4; ++nt) acc1[nt] = (f32x4){0.f, 0.f, 0.f, 0.f};
#pragma unroll
  for (int nt = 0; nt < 4; ++nt)
#pragma unroll
    for (int kt = 0; kt < 4; ++kt)
      acc1[nt] = __builtin_amdgcn_mfma_f32_16x16x32_bf16(am[kt], bn1[kt][nt], acc1[nt], 0, 0, 0);

  // h1 = silu(acc1 + b_n1) -> LDS transpose -> A-frags
#pragma unroll
  for (int nt = 0; nt < 4; ++nt)
#pragma unroll
    for (int j = 0; j < 4; ++j)
      sb[(lg * 4 + j) * 72 + nt * 16 + lr] = f2bs(silu_f(acc1[nt][j] + bn1c[nt]));
  const bf16x8 a20 = *(const bf16x8*)(sb + lr * 72 + lg * 8);
  const bf16x8 a21 = *(const bf16x8*)(sb + lr * 72 + 32 + lg * 8);

  f32x4 acc2[4];
#pragma unroll
  for (int nt = 0; nt < 4; ++nt) acc2[nt] = (f32x4){0.f, 0.f, 0.f, 0.f};
#pragma unroll
  for (int nt = 0; nt < 4; ++nt) {
    acc2[nt] = __builtin_amdgcn_mfma_f32_16x16x32_bf16(a20, bn2[0][nt], acc2[nt], 0, 0, 0);
    acc2[nt] = __builtin_amdgcn_mfma_f32_16x16x32_bf16(a21, bn2[1][nt], acc2[nt], 0, 0, 0);
  }
#pragma unroll
  for (int nt = 0; nt < 4; ++nt)
#pragma unroll
    for (int j = 0; j < 4; ++j)
      fb[(lg * 4 + j) * 68 + nt * 16 + lr] = acc2[nt][j] + bn2c[nt];
  {
    const int row = l >> 2, cs = (l & 3) * 16;
    float* dst = m_buf + (size_t)(tile * 16 + row) * 64 + cs;
#pragma unroll
    for (int q = 0; q < 4; ++q)
      *(float4*)(dst + q * 4) = *(const float4*)(fb + row * 68 + cs + q * 4);
  }
}

// K4b: wave per edge, lane = h. norms via 16-wide multi-butterfly.
__global__ __launch_bounds__(256) void k_edge_b(
    const bf16* __restrict__ cji2, const float* __restrict__ robs,
    const float* __restrict__ onew_buf, const float* __restrict__ m_buf,
    const int* __restrict__ idx_i, float* __restrict__ lacc) {
  const int wid = (blockIdx.x * 256 + threadIdx.x) >> 6;
  const int l = threadIdx.x & 63;
  if (wid >= EE) return;
  const float onew = onew_buf[(size_t)wid * 64 + l];
  const float m = m_buf[(size_t)wid * 64 + l];
  float4 rb[4];
#pragma unroll
  for (int q = 0; q < 4; ++q)
    rb[q] = *(const float4*)(robs + (size_t)wid * DD + q * 4);
  float v[16], sq[16];
#pragma unroll
  for (int d = 0; d < DD; ++d) {
    const float c =
        __bfloat162float(cji2[(size_t)wid * (DD * CC) + d * CC + l]);
    v[d] = c * onew;
    sq[d] = v[d] * v[d];
  }
#pragma unroll
  for (int step = 1; step < 64; step <<= 1)
#pragma unroll
    for (int d = 0; d < DD; ++d) sq[d] += __shfl_xor(sq[d], step, 64);
  float lc = 0.f;
#pragma unroll
  for (int d = 0; d < DD; ++d) {
    const float rbv = (d & 2) ? ((d & 1) ? rb[d >> 2].w : rb[d >> 2].z)
                              : ((d & 1) ? rb[d >> 2].y : rb[d >> 2].x);
    lc = fmaf(rbv * rnorm_f(sq[d]), v[d], lc);
  }
  const float ss = wave_sum64(lc * lc);
  const float lcao = lc * rnorm_f(ss);
  atomicAdd(&lacc[(size_t)idx_i[wid] * CC + l], lcao * m);
}

// K5: out = x + lacc @ W_na
__global__ __launch_bounds__(128) void k_out(
    const float* __restrict__ x, const float* __restrict__ lacc,
    const float* __restrict__ W_na, float* __restrict__ out) {
  __shared__ float lrow[CC];
  const int n = blockIdx.x;
  const int t = threadIdx.x;
  if (t < CC) lrow[t] = lacc[(size_t)n * CC + t];
  __syncthreads();
  float acc = x[(size_t)n * HH + t];
#pragma unroll 8
  for (int k = 0; k < CC; ++k) acc = fmaf(lrow[k], W_na[k * HH + t], acc);
  out[(size_t)n * HH + t] = acc;
}

extern "C" void kernel_launch(void* const* d_in, const int* in_sizes, int n_in,
                              void* d_out, int out_size, void* d_ws,
                              size_t ws_size, hipStream_t stream) {
  const float* x = (const float*)d_in[0];
  const float* cji = (const float*)d_in[1];
  const float* robs = (const float*)d_in[2];
  const float* shbs = (const float*)d_in[3];
  const int* idx_i = (const int*)d_in[4];
  const int* idx_j = (const int*)d_in[5];
  const int* tri_idx_k = (const int*)d_in[6];
  const int* edge_idx_kj = (const int*)d_in[7];
  const int* edge_idx_ji = (const int*)d_in[8];
  const float* W_nb = (const float*)d_in[9];
  const float* b_nb = (const float*)d_in[10];
  const float* W_c1 = (const float*)d_in[11];
  const float* W_c2 = (const float*)d_in[12];
  const float* W_t3 = (const float*)d_in[13];
  const float* b_t3 = (const float*)d_in[14];
  const float* W_n1 = (const float*)d_in[15];
  const float* b_n1 = (const float*)d_in[16];
  const float* W_n2 = (const float*)d_in[17];
  const float* b_n2 = (const float*)d_in[18];
  const float* W_na = (const float*)d_in[19];
  float* out = (float*)d_out;

  char* ws = (char*)d_ws;
  const size_t NC4 = (size_t)NN * CC * 4;          // 2,560,000
  const size_t EDC2 = (size_t)EE * DD * CC * 2;    // 102,400,000
  const size_t EC4 = (size_t)EE * CC * 4;          // 12,800,000
  float* sxq = (float*)(ws);
  float* sigxk = (float*)(ws + NC4);
  bf16* cji2 = (bf16*)(ws + 2 * NC4);
  bf16* ckjn = (bf16*)(ws + 2 * NC4 + EDC2);
  float* agg = (float*)(ws + 2 * NC4 + 2 * EDC2);
  float* lacc = (float*)(ws + 2 * NC4 + 2 * EDC2 + EC4);
  // onew/m overlay ckjn's region (ckjn is dead after k_triplet)
  float* onew_buf = (float*)(ws + 2 * NC4 + EDC2);
  float* m_buf = (float*)(ws + 2 * NC4 + EDC2 + EC4);

  hipMemsetAsync(agg, 0, EC4 + NC4, stream);

  k_node<<<NN, 128, 0, stream>>>(x, W_nb, b_nb, sxq, sigxk);
  k_coeffs<<<K2_BLOCKS, 256, 0, stream>>>(cji, W_c1, W_c2, cji2, ckjn);
  k_triplet<<<(TT + 3) / 4, 256, 0, stream>>>(ckjn, shbs, robs, sigxk,
                                              tri_idx_k, edge_idx_kj,
                                              edge_idx_ji, agg);
  k_edge_a<<<(K4A_TILES + 3) / 4, 256, 0, stream>>>(
      agg, sxq, idx_i, idx_j, W_t3, b_t3, W_n1, b_n1, W_n2, b_n2, onew_buf,
      m_buf);
  k_edge_b<<<EE / 4, 256, 0, stream>>>(cji2, robs, onew_buf, m_buf, idx_i,
                                       lacc);
  k_out<<<NN, 128, 0, stream>>>(x, lacc, W_na, out);
}

// Round 4
// 232.245 us; speedup vs baseline: 24.4472x; 1.2087x over previous
//
#include <hip/hip_runtime.h>
#include <hip/hip_bf16.h>

#define NN 10000
#define EE 50000
#define TT 80000
#define DD 16
#define HH 128
#define CC 64

typedef __hip_bfloat16 bf16;
typedef __attribute__((ext_vector_type(8))) short bf16x8;
typedef __attribute__((ext_vector_type(4))) float f32x4;

__device__ __forceinline__ float silu_f(float x) { return x / (1.f + __expf(-x)); }
__device__ __forceinline__ float sigm_f(float x) { return 1.f / (1.f + __expf(-x)); }

__device__ __forceinline__ short f2bs(float x) {
  __hip_bfloat16 h = __float2bfloat16(x);
  short s;
  __builtin_memcpy(&s, &h, 2);
  return s;
}

__device__ __forceinline__ float rnorm_f(float ss) {
  return __builtin_amdgcn_rcpf(fmaxf(__builtin_amdgcn_sqrtf(ss), 1e-12f));
}

__device__ __forceinline__ float wave_sum64(float v) {
#pragma unroll
  for (int m = 1; m < 64; m <<= 1) v += __shfl_xor(v, m, 64);
  return v;
}

// unpack a uint holding 2 bf16 into 2 floats (shift trick, no cvt)
__device__ __forceinline__ void bf2x(unsigned u, float& lo, float& hi) {
  lo = __uint_as_float(u << 16);
  hi = __uint_as_float(u & 0xffff0000u);
}

// K1: h = x @ W_nb + b_nb ; sxq = silu(h[:, :64]), sigxk = sigmoid(h[:, 64:])
__global__ __launch_bounds__(128) void k_node(
    const float* __restrict__ x, const float* __restrict__ W_nb,
    const float* __restrict__ b_nb, float* __restrict__ sxq,
    float* __restrict__ sigxk) {
  __shared__ float xrow[HH];
  const int n = blockIdx.x;
  const int t = threadIdx.x;
  xrow[t] = x[(size_t)n * HH + t];
  __syncthreads();
  float acc = b_nb[t];
#pragma unroll 8
  for (int k = 0; k < HH; ++k) acc = fmaf(xrow[k], W_nb[k * HH + t], acc);
  if (t < CC)
    sxq[(size_t)n * CC + t] = silu_f(acc);
  else
    sigxk[(size_t)n * CC + (t - CC)] = sigm_f(acc);
}

// K2 (MFMA): coeffs MLP over the [E*D, 64] matrix, 16-row tiles (tile == edge).
// Outputs cji2/ckjn stored in D-fragment PATCH layout:
//   value (row r, col c) -> lane (r>>2)*16 + (c&15), slot (c>>4)*4 + (r&3);
//   lane l's 16 bf16 contiguous at [tile*1024 + l*16].
#define K2_BLOCKS 2048
#define K2_TILES 50000  // (EE*DD)/16
__global__ __launch_bounds__(256, 2) void k_coeffs(
    const float* __restrict__ cji, const float* __restrict__ W_c1,
    const float* __restrict__ W_c2, bf16* __restrict__ cji2,
    bf16* __restrict__ ckjn) {
  __shared__ __align__(16) short xbuf[4][16 * 72];
  const int tid = threadIdx.x;
  const int w = tid >> 6, l = tid & 63;
  const int lr = l & 15, lg = l >> 4;
  short* mybuf = xbuf[w];

  bf16x8 b1[2][4];   // W_c1 [64][64]
  bf16x8 b2[2][8];   // W_c2 [64][128]
#pragma unroll
  for (int kt = 0; kt < 2; ++kt) {
#pragma unroll
    for (int nt = 0; nt < 4; ++nt) {
      bf16x8 t;
#pragma unroll
      for (int b = 0; b < 8; ++b)
        t[b] = f2bs(W_c1[(kt * 32 + lg * 8 + b) * 64 + nt * 16 + lr]);
      b1[kt][nt] = t;
    }
#pragma unroll
    for (int nt = 0; nt < 8; ++nt) {
      bf16x8 t;
#pragma unroll
      for (int b = 0; b < 8; ++b)
        t[b] = f2bs(W_c2[(kt * 32 + lg * 8 + b) * 128 + nt * 16 + lr]);
      b2[kt][nt] = t;
    }
  }

  const int nwave = K2_BLOCKS * 4;
  int tile = blockIdx.x * 4 + w;
  if (tile >= K2_TILES) return;

  float4 r0, r1, r2, r3;
  {
    const float* Ab = cji + (size_t)tile * 16 * 64 + lr * 64 + lg * 8;
    r0 = *(const float4*)(Ab);
    r1 = *(const float4*)(Ab + 4);
    r2 = *(const float4*)(Ab + 32);
    r3 = *(const float4*)(Ab + 36);
  }

  for (; tile < K2_TILES; tile += nwave) {
    bf16x8 a0, a1;
    a0[0] = f2bs(silu_f(r0.x)); a0[1] = f2bs(silu_f(r0.y));
    a0[2] = f2bs(silu_f(r0.z)); a0[3] = f2bs(silu_f(r0.w));
    a0[4] = f2bs(silu_f(r1.x)); a0[5] = f2bs(silu_f(r1.y));
    a0[6] = f2bs(silu_f(r1.z)); a0[7] = f2bs(silu_f(r1.w));
    a1[0] = f2bs(silu_f(r2.x)); a1[1] = f2bs(silu_f(r2.y));
    a1[2] = f2bs(silu_f(r2.z)); a1[3] = f2bs(silu_f(r2.w));
    a1[4] = f2bs(silu_f(r3.x)); a1[5] = f2bs(silu_f(r3.y));
    a1[6] = f2bs(silu_f(r3.z)); a1[7] = f2bs(silu_f(r3.w));

    const int next = tile + nwave;
    if (next < K2_TILES) {
      const float* Ab = cji + (size_t)next * 16 * 64 + lr * 64 + lg * 8;
      r0 = *(const float4*)(Ab);
      r1 = *(const float4*)(Ab + 4);
      r2 = *(const float4*)(Ab + 32);
      r3 = *(const float4*)(Ab + 36);
    }

    f32x4 acc1[4];
#pragma unroll
    for (int nt = 0; nt < 4; ++nt) acc1[nt] = (f32x4){0.f, 0.f, 0.f, 0.f};
#pragma unroll
    for (int nt = 0; nt < 4; ++nt) {
      acc1[nt] = __builtin_amdgcn_mfma_f32_16x16x32_bf16(a0, b1[0][nt], acc1[nt], 0, 0, 0);
      acc1[nt] = __builtin_amdgcn_mfma_f32_16x16x32_bf16(a1, b1[1][nt], acc1[nt], 0, 0, 0);
    }

    // t1 = silu(acc1): D-layout -> A-layout transpose via per-wave LDS
#pragma unroll
    for (int nt = 0; nt < 4; ++nt)
#pragma unroll
      for (int j = 0; j < 4; ++j)
        mybuf[(lg * 4 + j) * 72 + nt * 16 + lr] = f2bs(silu_f(acc1[nt][j]));

    bf16x8 a20 = *(const bf16x8*)(mybuf + lr * 72 + lg * 8);
    bf16x8 a21 = *(const bf16x8*)(mybuf + lr * 72 + 32 + lg * 8);

    f32x4 acc2[8];
#pragma unroll
    for (int nt = 0; nt < 8; ++nt) acc2[nt] = (f32x4){0.f, 0.f, 0.f, 0.f};
#pragma unroll
    for (int nt = 0; nt < 8; ++nt) {
      acc2[nt] = __builtin_amdgcn_mfma_f32_16x16x32_bf16(a20, b2[0][nt], acc2[nt], 0, 0, 0);
      acc2[nt] = __builtin_amdgcn_mfma_f32_16x16x32_bf16(a21, b2[1][nt], acc2[nt], 0, 0, 0);
    }

    float rn[4];
#pragma unroll
    for (int j = 0; j < 4; ++j) {
      float ss = acc2[4][j] * acc2[4][j];
      ss = fmaf(acc2[5][j], acc2[5][j], ss);
      ss = fmaf(acc2[6][j], acc2[6][j], ss);
      ss = fmaf(acc2[7][j], acc2[7][j], ss);
#pragma unroll
      for (int m = 1; m < 16; m <<= 1) ss += __shfl_xor(ss, m, 64);
      rn[j] = rnorm_f(ss);
    }

    // D-patch pack: 16 bf16/lane, contiguous 32B, zero LDS
    union { short h[16]; uint4 u[2]; } p;
#pragma unroll
    for (int nt = 0; nt < 4; ++nt)
#pragma unroll
      for (int j = 0; j < 4; ++j) p.h[nt * 4 + j] = f2bs(acc2[nt][j]);
    {
      uint4* d0 = (uint4*)(cji2 + (size_t)tile * 1024 + l * 16);
      d0[0] = p.u[0];
      d0[1] = p.u[1];
    }
#pragma unroll
    for (int nt = 0; nt < 4; ++nt)
#pragma unroll
      for (int j = 0; j < 4; ++j) p.h[nt * 4 + j] = f2bs(acc2[4 + nt][j] * rn[j]);
    {
      uint4* d1 = (uint4*)(ckjn + (size_t)tile * 1024 + l * 16);
      d1[0] = p.u[0];
      d1[1] = p.u[1];
    }
  }
}

// K3: one wave per triplet, ckjn in patch layout.
__global__ __launch_bounds__(256) void k_triplet(
    const bf16* __restrict__ ckjn, const float* __restrict__ shbs,
    const float* __restrict__ robs, const float* __restrict__ sigxk,
    const int* __restrict__ tri_idx_k, const int* __restrict__ edge_idx_kj,
    const int* __restrict__ edge_idx_ji, float* __restrict__ agg) {
  const int wid = (blockIdx.x * 256 + threadIdx.x) >> 6;
  const int l = threadIdx.x & 63;
  if (wid >= TT) return;
  const int lq = l >> 4, lr = l & 15;
  const int kj = edge_idx_kj[wid];
  const int kn = tri_idx_k[wid];
  const int ji = edge_idx_ji[wid];
  // weights for this lane's 4 rows d = lq*4 + {0..3}
  const float4 sh = *(const float4*)(shbs + (size_t)wid * DD + lq * 4);
  const float4 rb = *(const float4*)(robs + (size_t)kj * DD + lq * 4);
  const float w0 = sh.x * rb.x, w1 = sh.y * rb.y, w2 = sh.z * rb.z,
              w3 = sh.w * rb.w;
  const uint4* base = (const uint4*)(ckjn + (size_t)kj * 1024 + l * 16);
  const uint4 u0 = base[0], u1 = base[1];
  // acc[q] = partial (over this lane's 4 rows) for col q*16+lr
  float acc[4];
  {
    float x0, x1, x2, x3;
    bf2x(u0.x, x0, x1); bf2x(u0.y, x2, x3);
    acc[0] = fmaf(w3, x3, fmaf(w2, x2, fmaf(w1, x1, w0 * x0)));
    bf2x(u0.z, x0, x1); bf2x(u0.w, x2, x3);
    acc[1] = fmaf(w3, x3, fmaf(w2, x2, fmaf(w1, x1, w0 * x0)));
    bf2x(u1.x, x0, x1); bf2x(u1.y, x2, x3);
    acc[2] = fmaf(w3, x3, fmaf(w2, x2, fmaf(w1, x1, w0 * x0)));
    bf2x(u1.z, x0, x1); bf2x(u1.w, x2, x3);
    acc[3] = fmaf(w3, x3, fmaf(w2, x2, fmaf(w1, x1, w0 * x0)));
  }
  // reduce over the 4 row-groups (lanes differing in bits 4,5)
#pragma unroll
  for (int m = 16; m < 64; m <<= 1)
#pragma unroll
    for (int q = 0; q < 4; ++q) acc[q] += __shfl_xor(acc[q], m, 64);
  // col == l when picking q = lq
  const float sel = (lq == 0) ? acc[0] : (lq == 1) ? acc[1] : (lq == 2) ? acc[2] : acc[3];
  const float ss = wave_sum64(sel * sel);
  const float tbw = sel * rnorm_f(ss) * sigxk[(size_t)kn * CC + l];
  atomicAdd(&agg[(size_t)ji * CC + l], tbw);
}

// K4a (MFMA, 16 edges/wave): onew = 1 + silu(agg)@W_t3 + b_t3
//                            m    = silu(silu-cat(sxq_i,sxq_j)@W_n1+b_n1)@W_n2+b_n2
#define K4A_TILES 3125  // EE/16
__global__ __launch_bounds__(256, 2) void k_edge_a(
    const float* __restrict__ agg, const float* __restrict__ sxq,
    const int* __restrict__ idx_i, const int* __restrict__ idx_j,
    const float* __restrict__ W_t3, const float* __restrict__ b_t3,
    const float* __restrict__ W_n1, const float* __restrict__ b_n1,
    const float* __restrict__ W_n2, const float* __restrict__ b_n2,
    float* __restrict__ onew_buf, float* __restrict__ m_buf) {
  __shared__ __align__(16) float fbuf[4][16 * 68];
  __shared__ __align__(16) short sbuf[4][16 * 72];
  const int tid = threadIdx.x;
  const int w = tid >> 6, l = tid & 63;
  const int lr = l & 15, lg = l >> 4;
  float* fb = fbuf[w];
  short* sb = sbuf[w];
  const int tile = blockIdx.x * 4 + w;
  if (tile >= K4A_TILES) return;

  bf16x8 bt3[2][4], bn1[4][4], bn2[2][4];
#pragma unroll
  for (int kt = 0; kt < 2; ++kt)
#pragma unroll
    for (int nt = 0; nt < 4; ++nt) {
      bf16x8 t;
#pragma unroll
      for (int b = 0; b < 8; ++b)
        t[b] = f2bs(W_t3[(kt * 32 + lg * 8 + b) * 64 + nt * 16 + lr]);
      bt3[kt][nt] = t;
    }
#pragma unroll
  for (int kt = 0; kt < 4; ++kt)
#pragma unroll
    for (int nt = 0; nt < 4; ++nt) {
      bf16x8 t;
#pragma unroll
      for (int b = 0; b < 8; ++b)
        t[b] = f2bs(W_n1[(kt * 32 + lg * 8 + b) * 64 + nt * 16 + lr]);
      bn1[kt][nt] = t;
    }
#pragma unroll
  for (int kt = 0; kt < 2; ++kt)
#pragma unroll
    for (int nt = 0; nt < 4; ++nt) {
      bf16x8 t;
#pragma unroll
      for (int b = 0; b < 8; ++b)
        t[b] = f2bs(W_n2[(kt * 32 + lg * 8 + b) * 64 + nt * 16 + lr]);
      bn2[kt][nt] = t;
    }
  float bt3c[4], bn1c[4], bn2c[4];
#pragma unroll
  for (int nt = 0; nt < 4; ++nt) {
    bt3c[nt] = b_t3[nt * 16 + lr];
    bn1c[nt] = b_n1[nt * 16 + lr];
    bn2c[nt] = b_n2[nt * 16 + lr];
  }

  const int e = tile * 16 + lr;
  const int vi = idx_i[e], vj = idx_j[e];

  bf16x8 aagg[2];
#pragma unroll
  for (int kt = 0; kt < 2; ++kt) {
    const float4 u = *(const float4*)(agg + (size_t)e * 64 + kt * 32 + lg * 8);
    const float4 v = *(const float4*)(agg + (size_t)e * 64 + kt * 32 + lg * 8 + 4);
    bf16x8 t;
    t[0] = f2bs(silu_f(u.x)); t[1] = f2bs(silu_f(u.y));
    t[2] = f2bs(silu_f(u.z)); t[3] = f2bs(silu_f(u.w));
    t[4] = f2bs(silu_f(v.x)); t[5] = f2bs(silu_f(v.y));
    t[6] = f2bs(silu_f(v.z)); t[7] = f2bs(silu_f(v.w));
    aagg[kt] = t;
  }
  f32x4 acc[4];
#pragma unroll
  for (int nt = 0; nt < 4; ++nt) acc[nt] = (f32x4){0.f, 0.f, 0.f, 0.f};
#pragma unroll
  for (int nt = 0; nt < 4; ++nt) {
    acc[nt] = __builtin_amdgcn_mfma_f32_16x16x32_bf16(aagg[0], bt3[0][nt], acc[nt], 0, 0, 0);
    acc[nt] = __builtin_amdgcn_mfma_f32_16x16x32_bf16(aagg[1], bt3[1][nt], acc[nt], 0, 0, 0);
  }
#pragma unroll
  for (int nt = 0; nt < 4; ++nt)
#pragma unroll
    for (int j = 0; j < 4; ++j)
      fb[(lg * 4 + j) * 68 + nt * 16 + lr] = 1.f + bt3c[nt] + acc[nt][j];
  {
    const int row = l >> 2, cs = (l & 3) * 16;
    float* dst = onew_buf + (size_t)(tile * 16 + row) * 64 + cs;
#pragma unroll
    for (int q = 0; q < 4; ++q)
      *(float4*)(dst + q * 4) = *(const float4*)(fb + row * 68 + cs + q * 4);
  }

  bf16x8 am[4];
#pragma unroll
  for (int kt = 0; kt < 4; ++kt) {
    const float* src = (kt < 2) ? (sxq + (size_t)vi * 64 + kt * 32)
                                : (sxq + (size_t)vj * 64 + (kt - 2) * 32);
    const float4 u = *(const float4*)(src + lg * 8);
    const float4 v = *(const float4*)(src + lg * 8 + 4);
    bf16x8 t;
    t[0] = f2bs(u.x); t[1] = f2bs(u.y); t[2] = f2bs(u.z); t[3] = f2bs(u.w);
    t[4] = f2bs(v.x); t[5] = f2bs(v.y); t[6] = f2bs(v.z); t[7] = f2bs(v.w);
    am[kt] = t;
  }
  f32x4 acc1[4];
#pragma unroll
  for (int nt = 0; nt < 4; ++nt) acc1[nt] = (f32x4){0.f, 0.f, 0.f, 0.f};
#pragma unroll
  for (int nt = 0; nt < 4; ++nt)
#pragma unroll
    for (int kt = 0; kt < 4; ++kt)
      acc1[nt] = __builtin_amdgcn_mfma_f32_16x16x32_bf16(am[kt], bn1[kt][nt], acc1[nt], 0, 0, 0);

#pragma unroll
  for (int nt = 0; nt < 4; ++nt)
#pragma unroll
    for (int j = 0; j < 4; ++j)
      sb[(lg * 4 + j) * 72 + nt * 16 + lr] = f2bs(silu_f(acc1[nt][j] + bn1c[nt]));
  const bf16x8 a20 = *(const bf16x8*)(sb + lr * 72 + lg * 8);
  const bf16x8 a21 = *(const bf16x8*)(sb + lr * 72 + 32 + lg * 8);

  f32x4 acc2[4];
#pragma unroll
  for (int nt = 0; nt < 4; ++nt) acc2[nt] = (f32x4){0.f, 0.f, 0.f, 0.f};
#pragma unroll
  for (int nt = 0; nt < 4; ++nt) {
    acc2[nt] = __builtin_amdgcn_mfma_f32_16x16x32_bf16(a20, bn2[0][nt], acc2[nt], 0, 0, 0);
    acc2[nt] = __builtin_amdgcn_mfma_f32_16x16x32_bf16(a21, bn2[1][nt], acc2[nt], 0, 0, 0);
  }
#pragma unroll
  for (int nt = 0; nt < 4; ++nt)
#pragma unroll
    for (int j = 0; j < 4; ++j)
      fb[(lg * 4 + j) * 68 + nt * 16 + lr] = acc2[nt][j] + bn2c[nt];
  {
    const int row = l >> 2, cs = (l & 3) * 16;
    float* dst = m_buf + (size_t)(tile * 16 + row) * 64 + cs;
#pragma unroll
    for (int q = 0; q < 4; ++q)
      *(float4*)(dst + q * 4) = *(const float4*)(fb + row * 68 + cs + q * 4);
  }
}

// K4b: wave per edge, cji2 in patch layout; lane owns a 4x4 patch.
__global__ __launch_bounds__(256) void k_edge_b(
    const bf16* __restrict__ cji2, const float* __restrict__ robs,
    const float* __restrict__ onew_buf, const float* __restrict__ m_buf,
    const int* __restrict__ idx_i, float* __restrict__ lacc) {
  const int wid = (blockIdx.x * 256 + threadIdx.x) >> 6;
  const int l = threadIdx.x & 63;
  if (wid >= EE) return;
  const int lq = l >> 4, lr = l & 15;
  const uint4* base = (const uint4*)(cji2 + (size_t)wid * 1024 + l * 16);
  const uint4 u0 = base[0], u1 = base[1];
  // onew for this lane's 4 cols q*16+lr
  const float* ob = onew_buf + (size_t)wid * 64 + lr;
  const float ow0 = ob[0], ow1 = ob[16], ow2 = ob[32], ow3 = ob[48];
  float v[16];
  bf2x(u0.x, v[0], v[1]);  bf2x(u0.y, v[2], v[3]);
  bf2x(u0.z, v[4], v[5]);  bf2x(u0.w, v[6], v[7]);
  bf2x(u1.x, v[8], v[9]);  bf2x(u1.y, v[10], v[11]);
  bf2x(u1.z, v[12], v[13]); bf2x(u1.w, v[14], v[15]);
#pragma unroll
  for (int j = 0; j < 4; ++j) {
    v[j] *= ow0; v[4 + j] *= ow1; v[8 + j] *= ow2; v[12 + j] *= ow3;
  }
  // per-row (d = lq*4 + j) sum of squares: partial over 4 cols, butterfly 16
  float sq[4];
#pragma unroll
  for (int j = 0; j < 4; ++j)
    sq[j] = fmaf(v[j], v[j],
            fmaf(v[4 + j], v[4 + j],
            fmaf(v[8 + j], v[8 + j], v[12 + j] * v[12 + j])));
#pragma unroll
  for (int m = 1; m < 16; m <<= 1)
#pragma unroll
    for (int j = 0; j < 4; ++j) sq[j] += __shfl_xor(sq[j], m, 64);
  const float4 rb = *(const float4*)(robs + (size_t)wid * DD + lq * 4);
  const float t0 = rb.x * rnorm_f(sq[0]), t1 = rb.y * rnorm_f(sq[1]),
              t2 = rb.z * rnorm_f(sq[2]), t3 = rb.w * rnorm_f(sq[3]);
  // lc partial per col q over this lane's 4 rows
  float lcq[4];
#pragma unroll
  for (int q = 0; q < 4; ++q)
    lcq[q] = fmaf(t0, v[q * 4 + 0],
             fmaf(t1, v[q * 4 + 1],
             fmaf(t2, v[q * 4 + 2], t3 * v[q * 4 + 3])));
#pragma unroll
  for (int m = 16; m < 64; m <<= 1)
#pragma unroll
    for (int q = 0; q < 4; ++q) lcq[q] += __shfl_xor(lcq[q], m, 64);
  const float sel = (lq == 0) ? lcq[0] : (lq == 1) ? lcq[1] : (lq == 2) ? lcq[2] : lcq[3];
  const float ss = wave_sum64(sel * sel);
  const float lcao = sel * rnorm_f(ss);
  atomicAdd(&lacc[(size_t)idx_i[wid] * CC + l],
            lcao * m_buf[(size_t)wid * 64 + l]);
}

// K5: out = x + lacc @ W_na
__global__ __launch_bounds__(128) void k_out(
    const float* __restrict__ x, const float* __restrict__ lacc,
    const float* __restrict__ W_na, float* __restrict__ out) {
  __shared__ float lrow[CC];
  const int n = blockIdx.x;
  const int t = threadIdx.x;
  if (t < CC) lrow[t] = lacc[(size_t)n * CC + t];
  __syncthreads();
  float acc = x[(size_t)n * HH + t];
#pragma unroll 8
  for (int k = 0; k < CC; ++k) acc = fmaf(lrow[k], W_na[k * HH + t], acc);
  out[(size_t)n * HH + t] = acc;
}

extern "C" void kernel_launch(void* const* d_in, const int* in_sizes, int n_in,
                              void* d_out, int out_size, void* d_ws,
                              size_t ws_size, hipStream_t stream) {
  const float* x = (const float*)d_in[0];
  const float* cji = (const float*)d_in[1];
  const float* robs = (const float*)d_in[2];
  const float* shbs = (const float*)d_in[3];
  const int* idx_i = (const int*)d_in[4];
  const int* idx_j = (const int*)d_in[5];
  const int* tri_idx_k = (const int*)d_in[6];
  const int* edge_idx_kj = (const int*)d_in[7];
  const int* edge_idx_ji = (const int*)d_in[8];
  const float* W_nb = (const float*)d_in[9];
  const float* b_nb = (const float*)d_in[10];
  const float* W_c1 = (const float*)d_in[11];
  const float* W_c2 = (const float*)d_in[12];
  const float* W_t3 = (const float*)d_in[13];
  const float* b_t3 = (const float*)d_in[14];
  const float* W_n1 = (const float*)d_in[15];
  const float* b_n1 = (const float*)d_in[16];
  const float* W_n2 = (const float*)d_in[17];
  const float* b_n2 = (const float*)d_in[18];
  const float* W_na = (const float*)d_in[19];
  float* out = (float*)d_out;

  char* ws = (char*)d_ws;
  const size_t NC4 = (size_t)NN * CC * 4;          // 2,560,000
  const size_t EDC2 = (size_t)EE * DD * CC * 2;    // 102,400,000
  const size_t EC4 = (size_t)EE * CC * 4;          // 12,800,000
  float* sxq = (float*)(ws);
  float* sigxk = (float*)(ws + NC4);
  bf16* cji2 = (bf16*)(ws + 2 * NC4);
  bf16* ckjn = (bf16*)(ws + 2 * NC4 + EDC2);
  float* agg = (float*)(ws + 2 * NC4 + 2 * EDC2);
  float* lacc = (float*)(ws + 2 * NC4 + 2 * EDC2 + EC4);
  // onew/m overlay ckjn's region (ckjn is dead after k_triplet)
  float* onew_buf = (float*)(ws + 2 * NC4 + EDC2);
  float* m_buf = (float*)(ws + 2 * NC4 + EDC2 + EC4);

  hipMemsetAsync(agg, 0, EC4 + NC4, stream);

  k_node<<<NN, 128, 0, stream>>>(x, W_nb, b_nb, sxq, sigxk);
  k_coeffs<<<K2_BLOCKS, 256, 0, stream>>>(cji, W_c1, W_c2, cji2, ckjn);
  k_triplet<<<(TT + 3) / 4, 256, 0, stream>>>(ckjn, shbs, robs, sigxk,
                                              tri_idx_k, edge_idx_kj,
                                              edge_idx_ji, agg);
  k_edge_a<<<(K4A_TILES + 3) / 4, 256, 0, stream>>>(
      agg, sxq, idx_i, idx_j, W_t3, b_t3, W_n1, b_n1, W_n2, b_n2, onew_buf,
      m_buf);
  k_edge_b<<<EE / 4, 256, 0, stream>>>(cji2, robs, onew_buf, m_buf, idx_i,
                                       lacc);
  k_out<<<NN, 128, 0, stream>>>(x, lacc, W_na, out);
}